// Round 14
// baseline (167.219 us; speedup 1.0000x reference)
//
#include <hip/hip_runtime.h>
#include <stdint.h>

#define B_  4
#define H_  16
#define N_  1024
#define D_  64
#define SS_R 328   // halfs per i-row of Ss: [i in 0..32)][j*20 + h], +8 pad
#define A2_R 328   // halfs per g-row of A2s: [g][i*20 + j], +8 pad

typedef _Float16 half4v __attribute__((ext_vector_type(4)));
typedef _Float16 half8v __attribute__((ext_vector_type(8)));
typedef float    f32x4  __attribute__((ext_vector_type(4)));

// workspace layout (bytes) — 8 MB region time-shared: Kh (sweep1) then VT (sweep2)
#define SH_OFF   0
#define SH_SZ    (B_ * H_ * N_ * D_ * 2)             // 8 MB
#define LB_OFF   (SH_OFF + SH_SZ)
#define LB_SZ    (B_ * H_ * N_ * 4)                  // 256 KB
#define E_OFF    (LB_OFF + LB_SZ)
#define E_SZ     ((size_t)B_ * 2080 * 4096 * 2)      // 65 MB causal-packed E
#define WS_NEED  ((size_t)E_OFF + E_SZ)              // 73.25 MB (proven available)

__device__ __forceinline__ half4v cvt4(f32x4 v) {
    half4v h;
    h[0] = (_Float16)v[0]; h[1] = (_Float16)v[1];
    h[2] = (_Float16)v[2]; h[3] = (_Float16)v[3];
    return h;
}

// decode blockIdx (0..511) -> slot grouped per XCD (consecutive slots same XCD)
__device__ __forceinline__ int xcd_slot(int x) { return (x >> 3) + (x & 7) * 64; }

// ---------------- prep: K to f16 (row-major, same layout) ----------------
__global__ __launch_bounds__(256)
void prep_kh(const float* __restrict__ k, _Float16* __restrict__ Kh) {
    const size_t idx = ((size_t)blockIdx.x * 256 + threadIdx.x) * 8;
    f32x4 a = *(const f32x4*)(k + idx);
    f32x4 b = *(const f32x4*)(k + idx + 4);
    half8v h;
    #pragma unroll
    for (int e = 0; e < 4; ++e) { h[e] = (_Float16)a[e]; h[4 + e] = (_Float16)b[e]; }
    *(half8v*)(Kh + idx) = h;
}

// ---------------- prep: V transpose to f16 VT[b,h,d,j] (runs AFTER sweep1) ----------------
__global__ __launch_bounds__(256)
void prep_vt(const float* __restrict__ v, _Float16* __restrict__ VT) {
    __shared__ float T[64 * 67];
    const int t = threadIdx.x;
    const int bh = blockIdx.x >> 4, jb = blockIdx.x & 15, j0 = jb * 64;
    const float* src = v + ((size_t)bh * N_ + j0) * D_;
    #pragma unroll
    for (int m = 0; m < 4; ++m) {
        const int flat = m * 1024 + t * 4;
        const int j = flat >> 6, d0 = flat & 63;
        f32x4 val = *(const f32x4*)(src + flat);
        #pragma unroll
        for (int e = 0; e < 4; ++e) T[j * 67 + d0 + e] = val[e];
    }
    __syncthreads();
    const int d = t >> 2, jq = t & 3;
    half8v a, b2;
    #pragma unroll
    for (int jj = 0; jj < 8; ++jj) a[jj]  = (_Float16)T[(16 * jq + jj) * 67 + d];
    #pragma unroll
    for (int jj = 0; jj < 8; ++jj) b2[jj] = (_Float16)T[(16 * jq + 8 + jj) * 67 + d];
    _Float16* dst = VT + ((size_t)bh * D_ + d) * N_ + j0 + jq * 16;
    *(half8v*)dst = a;
    *(half8v*)(dst + 8) = b2;
}

// ---------------- sweep 1: l (atomic) + E cache (f16, causal-packed) ----------------
// grid 512: phased mirror-pairs (R11-proven). K from f16 Kh workspace.
// E tile layout (halfs, 4096/tile): (i&7)*512 + j*32 + (h>>2)*8 + (i>>3)*4 + (h&3)
__global__ __launch_bounds__(512, 2)
void attend_sweep1(const float* __restrict__ q, const _Float16* __restrict__ Kh,
                   const float* __restrict__ Wpre, float* __restrict__ lbuf,
                   _Float16* __restrict__ Ebuf) {
    __shared__ _Float16 Ss[2][32 * SS_R];   // 41,984 B

    const int slot = xcd_slot(blockIdx.x);
    const int b = slot >> 7;
    const int r7 = slot & 127;
    const int m = r7 >> 2, phase = r7 & 3;
    const int itA = m, itB = 63 - m;
    const int i0A = m * 16, i0B = itB * 16;
    const int triA = itA * (itA + 1) / 2, triB = itB * (itB + 1) / 2;

    const int t = threadIdx.x;
    const int lane = t & 63, w = t >> 6;        // 8 waves
    const int l16 = lane & 15, lg = lane >> 4;
    const int h0 = 2 * w;
    const size_t bh0 = (size_t)b * H_;
    _Float16* Eb = Ebuf + (size_t)b * 2080 * 4096;

    const half4v wpre_f = cvt4(*(const f32x4*)(Wpre + l16 * 16 + 4 * lg));

    half4v qf[2][2][4];
    #pragma unroll
    for (int s = 0; s < 2; ++s) {
        const int i0s = s ? i0B : i0A;
        #pragma unroll
        for (int e = 0; e < 2; ++e) {
            const float* qrow = q + ((bh0 + h0 + e) * N_ + i0s + l16) * D_;
            #pragma unroll
            for (int kk = 0; kk < 4; ++kk) {
                f32x4 qv = *(const f32x4*)(qrow + kk * 16 + 4 * lg);
                half4v hv;
                #pragma unroll
                for (int xx = 0; xx < 4; ++xx) hv[xx] = (_Float16)(qv[xx] * 0.125f);
                qf[s][e][kk] = hv;
            }
        }
    }

    float lp[4][4];
    #pragma unroll
    for (int ss = 0; ss < 4; ++ss)
        #pragma unroll
        for (int r = 0; r < 4; ++r) lp[ss][r] = 0.f;

    int pbuf = 0;
    for (int sb = phase; 2 * sb <= itB; sb += 4) {
        #pragma unroll
        for (int u = 0; u < 2; ++u) {
            const int jt = 2 * sb + u;
            if (jt > itB) break;
            const int j0 = jt * 16;
            const bool actA = (jt <= itA);
            half4v kf[2][4];
            #pragma unroll
            for (int e = 0; e < 2; ++e) {
                const _Float16* krow = Kh + ((bh0 + h0 + e) * N_ + j0 + l16) * D_ + 4 * lg;
                #pragma unroll
                for (int kk = 0; kk < 4; ++kk) kf[e][kk] = *(const half4v*)(krow + kk * 16);
            }
            #pragma unroll
            for (int s = 0; s < 2; ++s) {
                if (s == 0 && !actA) continue;
                #pragma unroll
                for (int e = 0; e < 2; ++e) {
                    f32x4 acc = {0.f, 0.f, 0.f, 0.f};
                    #pragma unroll
                    for (int kk = 0; kk < 4; ++kk)
                        acc = __builtin_amdgcn_mfma_f32_16x16x16f16(qf[s][e][kk], kf[e][kk], acc, 0, 0, 0);
                    #pragma unroll
                    for (int r = 0; r < 4; ++r)
                        Ss[pbuf][(s * 16 + 4 * lg + r) * SS_R + l16 * 20 + h0 + e] = (_Float16)acc[r];
                }
            }
            __syncthreads();
            #pragma unroll
            for (int ss = 0; ss < 4; ++ss) {
                const int strip = ss >> 1;
                if (strip == 0 && !actA) continue;
                const int sii = (ss & 1) * 8 + w;
                const int its = strip ? itB : itA;
                const int tri = strip ? triB : triA;
                half4v sfrag = *(const half4v*)&Ss[pbuf][(strip * 16 + sii) * SS_R + l16 * 20 + 4 * lg];
                f32x4 z = {0.f, 0.f, 0.f, 0.f};
                f32x4 m1 = __builtin_amdgcn_mfma_f32_16x16x16f16(wpre_f, sfrag, z, 0, 0, 0);
                const bool ok = (jt < its) || (l16 <= sii);
                half4v ev;
                #pragma unroll
                for (int r = 0; r < 4; ++r) {
                    const float e_ = ok ? __expf(m1[r]) : 0.f;
                    lp[ss][r] += e_;
                    ev[r] = (_Float16)e_;
                }
                // permuted tile layout: w*512 + j*32 + hq*8 + ipar*4
                *(half4v*)(Eb + (size_t)(tri + jt) * 4096 + w * 512 + l16 * 32 + lg * 8 + (ss & 1) * 4) = ev;
            }
            pbuf ^= 1;
        }
    }

    #pragma unroll
    for (int ss = 0; ss < 4; ++ss) {
        const int strip = ss >> 1;
        const int sii = (ss & 1) * 8 + w;
        const int i0s = strip ? i0B : i0A;
        #pragma unroll
        for (int r = 0; r < 4; ++r) {
            float val = lp[ss][r];
            val += __shfl_xor(val, 1, 64);
            val += __shfl_xor(val, 2, 64);
            val += __shfl_xor(val, 4, 64);
            val += __shfl_xor(val, 8, 64);
            if (l16 == 0)
                atomicAdd(&lbuf[(bh0 + 4 * lg + r) * N_ + i0s + sii], val);
        }
    }
}

// ---------------- sweep 2: out = Wpost·(E/l)·V — R11-proven (4 blocks/CU) ----------------
// grid 1024: r=x>>4 balanced pairing, (b, d-quarter)=x&15. 16B E loads, E prefetch.
__global__ __launch_bounds__(512, 8)
void attend_sweep2(const _Float16* __restrict__ Ebuf, const _Float16* __restrict__ VT,
                   const float* __restrict__ Wpost, const float* __restrict__ lbuf,
                   float* __restrict__ out) {
    __shared__ _Float16 A2s[2][16 * A2_R];   // 20,992 B

    const int x = blockIdx.x;
    const int r_ = x >> 4;
    const int it = (r_ < 32) ? (63 - r_) : (r_ - 32);   // quadruple sums constant
    const int sub = x & 15;
    const int b = sub >> 2, dq = sub & 3;
    const int i0 = it * 16;

    const int t = threadIdx.x;
    const int lane = t & 63, w = t >> 6;      // 8 waves
    const int l16 = lane & 15, lg = lane >> 4;
    const int h0 = 2 * w;
    const size_t bh0 = (size_t)b * H_;

    const half4v wpost_f = cvt4(*(const f32x4*)(Wpost + l16 * 16 + 4 * lg));

    // 1/l for softmax head 4lg+r at rows i0+sii (sii = ss*8+w)
    float lrecip[2][4];
    #pragma unroll
    for (int ss = 0; ss < 2; ++ss) {
        const int sii = ss * 8 + w;
        #pragma unroll
        for (int r = 0; r < 4; ++r)
            lrecip[ss][r] = 1.0f / lbuf[(bh0 + 4 * lg + r) * N_ + i0 + sii];
    }

    const _Float16* Eb = Ebuf + ((size_t)b * 2080 + (size_t)it * (it + 1) / 2) * 4096
                       + w * 512 + l16 * 32 + lg * 8;

    f32x4 oacc[2];
    #pragma unroll
    for (int e = 0; e < 2; ++e) oacc[e] = (f32x4){0.f, 0.f, 0.f, 0.f};

    int pb = 0;
    // prologue: E(0) — one 16B load covers both sii fragments
    half8v ecur = *(const half8v*)(Eb);

    for (int jt = 0; jt <= it; ++jt) {
        // VT fragments for this jt (in flight under mix2 + barrier)
        half4v vf[2];
        #pragma unroll
        for (int e = 0; e < 2; ++e)
            vf[e] = *(const half4v*)(VT + ((bh0 + h0 + e) * D_ + dq * 16 + l16) * (size_t)N_ + jt * 16 + 4 * lg);
        // mix2 from prefetched E
        #pragma unroll
        for (int ss = 0; ss < 2; ++ss) {
            const int sii = ss * 8 + w;
            half4v pf;
            #pragma unroll
            for (int r = 0; r < 4; ++r)
                pf[r] = (_Float16)((float)ecur[ss * 4 + r] * lrecip[ss][r]);
            f32x4 z = {0.f, 0.f, 0.f, 0.f};
            f32x4 m2 = __builtin_amdgcn_mfma_f32_16x16x16f16(wpost_f, pf, z, 0, 0, 0);
            #pragma unroll
            for (int r = 0; r < 4; ++r)
                A2s[pb][(4 * lg + r) * A2_R + sii * 20 + l16] = (_Float16)m2[r];
        }
        // prefetch E(jt+1) — stays in flight across the barrier
        half8v enext = ecur;
        if (jt < it) enext = *(const half8v*)(Eb + (size_t)(jt + 1) * 4096);
        __syncthreads();
        // PV
        #pragma unroll
        for (int e = 0; e < 2; ++e) {
            const int g = h0 + e;
            half4v bfrag = *(const half4v*)&A2s[pb][g * A2_R + l16 * 20 + 4 * lg];
            oacc[e] = __builtin_amdgcn_mfma_f32_16x16x16f16(vf[e], bfrag, oacc[e], 0, 0, 0);
        }
        ecur = enext;
        pb ^= 1;
    }

    // plain stores — WG exclusively owns (b, it-rows, all g, this d-quarter)
    #pragma unroll
    for (int e = 0; e < 2; ++e) {
        float* orow = out + ((bh0 + h0 + e) * N_ + i0 + l16) * D_;
        *(f32x4*)&orow[dq * 16 + 4 * lg] = oacc[e];
    }
}

// ---------------- fallback: fused mirror-pair kernel (ws-free, verified R6) ----------------
__global__ __launch_bounds__(512, 2)
void attend_fused(const float* __restrict__ q, const float* __restrict__ k,
                  const float* __restrict__ v, const float* __restrict__ Wpre,
                  const float* __restrict__ Wpost, float* __restrict__ out) {
    __shared__ _Float16 Ss[32 * SS_R];
    __shared__ _Float16 A2s[16 * 648];

    const int t = threadIdx.x;
    const int b = blockIdx.x >> 5;
    const int m = blockIdx.x & 31;
    const int itA = m, itB = 63 - m;
    const int i0A = m * 16, i0B = (63 - m) * 16;

    const int lane = t & 63, w = t >> 6;
    const int l16 = lane & 15, lg = lane >> 4;
    const int h0 = 2 * w;
    const size_t bh0 = (size_t)b * H_;

    const half4v wpre_f  = cvt4(*(const f32x4*)(Wpre  + l16 * 16 + 4 * lg));
    const half4v wpost_f = cvt4(*(const f32x4*)(Wpost + l16 * 16 + 4 * lg));

    half4v qf[2][2][4];
    #pragma unroll
    for (int s = 0; s < 2; ++s) {
        const int i0s = s ? i0B : i0A;
        #pragma unroll
        for (int e = 0; e < 2; ++e) {
            const float* qrow = q + ((bh0 + h0 + e) * N_ + i0s + l16) * D_;
            #pragma unroll
            for (int kk = 0; kk < 4; ++kk) {
                f32x4 qv = *(const f32x4*)(qrow + kk * 16 + 4 * lg);
                half4v hv;
                #pragma unroll
                for (int xx = 0; xx < 4; ++xx) hv[xx] = (_Float16)(qv[xx] * 0.125f);
                qf[s][e][kk] = hv;
            }
        }
    }

    float lp[4][4];
    #pragma unroll
    for (int ss = 0; ss < 4; ++ss)
        #pragma unroll
        for (int r = 0; r < 4; ++r) lp[ss][r] = 0.f;

    for (int jt = 0; jt <= itB; ++jt) {
        const int j0 = jt * 16;
        const bool actA = (jt <= itA);
        half4v kf[2][4];
        #pragma unroll
        for (int e = 0; e < 2; ++e) {
            const float* krow = k + ((bh0 + h0 + e) * N_ + j0 + l16) * D_ + 4 * lg;
            #pragma unroll
            for (int kk = 0; kk < 4; ++kk) kf[e][kk] = cvt4(*(const f32x4*)(krow + kk * 16));
        }
        #pragma unroll
        for (int s = 0; s < 2; ++s) {
            if (s == 0 && !actA) continue;
            #pragma unroll
            for (int e = 0; e < 2; ++e) {
                f32x4 acc = {0.f, 0.f, 0.f, 0.f};
                #pragma unroll
                for (int kk = 0; kk < 4; ++kk)
                    acc = __builtin_amdgcn_mfma_f32_16x16x16f16(qf[s][e][kk], kf[e][kk], acc, 0, 0, 0);
                #pragma unroll
                for (int r = 0; r < 4; ++r)
                    Ss[(s * 16 + 4 * lg + r) * SS_R + l16 * 20 + h0 + e] = (_Float16)acc[r];
            }
        }
        __syncthreads();
        #pragma unroll
        for (int ss = 0; ss < 4; ++ss) {
            const int strip = ss >> 1;
            if (strip == 0 && !actA) continue;
            const int sii = (ss & 1) * 8 + w;
            const int its = strip ? itB : itA;
            half4v sfrag = *(const half4v*)&Ss[(strip * 16 + sii) * SS_R + l16 * 20 + 4 * lg];
            f32x4 z = {0.f, 0.f, 0.f, 0.f};
            f32x4 m1 = __builtin_amdgcn_mfma_f32_16x16x16f16(wpre_f, sfrag, z, 0, 0, 0);
            if ((jt < its) || (l16 <= sii)) {
                #pragma unroll
                for (int r = 0; r < 4; ++r) lp[ss][r] += __expf(m1[r]);
            }
        }
        __syncthreads();
    }

    float lrec[4][4];
    #pragma unroll
    for (int ss = 0; ss < 4; ++ss)
        #pragma unroll
        for (int r = 0; r < 4; ++r) {
            float val = lp[ss][r];
            val += __shfl_xor(val, 1, 64);
            val += __shfl_xor(val, 2, 64);
            val += __shfl_xor(val, 4, 64);
            val += __shfl_xor(val, 8, 64);
            lrec[ss][r] = 1.0f / val;
        }

    f32x4 oacc[2][2][4];
    #pragma unroll
    for (int s = 0; s < 2; ++s)
        #pragma unroll
        for (int e = 0; e < 2; ++e)
            #pragma unroll
            for (int ds = 0; ds < 4; ++ds)
                oacc[s][e][ds] = (f32x4){0.f, 0.f, 0.f, 0.f};

    for (int jt = 0; jt <= itB; ++jt) {
        const int j0 = jt * 16;
        const bool actA = (jt <= itA);
        half4v kf[2][4];
        #pragma unroll
        for (int e = 0; e < 2; ++e) {
            const float* krow = k + ((bh0 + h0 + e) * N_ + j0 + l16) * D_ + 4 * lg;
            #pragma unroll
            for (int kk = 0; kk < 4; ++kk) kf[e][kk] = cvt4(*(const f32x4*)(krow + kk * 16));
        }
        half4v vf[2][4];
        #pragma unroll
        for (int e = 0; e < 2; ++e)
            #pragma unroll
            for (int ds = 0; ds < 4; ++ds) {
                f32x4 vv;
                #pragma unroll
                for (int xx = 0; xx < 4; ++xx)
                    vv[xx] = v[((bh0 + h0 + e) * N_ + j0 + 4 * lg + xx) * D_ + ds * 16 + l16];
                vf[e][ds] = cvt4(vv);
            }
        #pragma unroll
        for (int s = 0; s < 2; ++s) {
            if (s == 0 && !actA) continue;
            #pragma unroll
            for (int e = 0; e < 2; ++e) {
                f32x4 acc = {0.f, 0.f, 0.f, 0.f};
                #pragma unroll
                for (int kk = 0; kk < 4; ++kk)
                    acc = __builtin_amdgcn_mfma_f32_16x16x16f16(qf[s][e][kk], kf[e][kk], acc, 0, 0, 0);
                #pragma unroll
                for (int r = 0; r < 4; ++r)
                    Ss[(s * 16 + 4 * lg + r) * SS_R + l16 * 20 + h0 + e] = (_Float16)acc[r];
            }
        }
        __syncthreads();
        #pragma unroll
        for (int ss = 0; ss < 4; ++ss) {
            const int strip = ss >> 1;
            if (strip == 0 && !actA) continue;
            const int sii = (ss & 1) * 8 + w;
            const int its = strip ? itB : itA;
            half4v sfrag = *(const half4v*)&Ss[(strip * 16 + sii) * SS_R + l16 * 20 + 4 * lg];
            f32x4 z = {0.f, 0.f, 0.f, 0.f};
            f32x4 m1 = __builtin_amdgcn_mfma_f32_16x16x16f16(wpre_f, sfrag, z, 0, 0, 0);
            const bool ok = (jt < its) || (l16 <= sii);
            half4v pfrag;
            #pragma unroll
            for (int r = 0; r < 4; ++r)
                pfrag[r] = (_Float16)(ok ? __expf(m1[r]) * lrec[ss][r] : 0.f);
            f32x4 m2 = __builtin_amdgcn_mfma_f32_16x16x16f16(wpost_f, pfrag, z, 0, 0, 0);
            #pragma unroll
            for (int r = 0; r < 4; ++r)
                A2s[(4 * lg + r) * 648 + (strip * 16 + sii) * 20 + l16] = (_Float16)m2[r];
        }
        __syncthreads();
        #pragma unroll
        for (int s = 0; s < 2; ++s) {
            if (s == 0 && !actA) continue;
            #pragma unroll
            for (int e = 0; e < 2; ++e) {
                half4v bfrag = *(const half4v*)&A2s[(h0 + e) * 648 + (s * 16 + l16) * 20 + 4 * lg];
                #pragma unroll
                for (int ds = 0; ds < 4; ++ds)
                    oacc[s][e][ds] = __builtin_amdgcn_mfma_f32_16x16x16f16(vf[e][ds], bfrag, oacc[s][e][ds], 0, 0, 0);
            }
        }
    }

    #pragma unroll
    for (int s = 0; s < 2; ++s) {
        const int i0s = s ? i0B : i0A;
        #pragma unroll
        for (int e = 0; e < 2; ++e) {
            float* orow = out + ((bh0 + h0 + e) * N_ + i0s + l16) * D_;
            #pragma unroll
            for (int ds = 0; ds < 4; ++ds)
                *(f32x4*)&orow[ds * 16 + 4 * lg] = oacc[s][e][ds];
        }
    }
}

extern "C" void kernel_launch(void* const* d_in, const int* in_sizes, int n_in,
                              void* d_out, int out_size, void* d_ws, size_t ws_size,
                              hipStream_t stream) {
    const float* q     = (const float*)d_in[0];
    const float* k     = (const float*)d_in[1];
    const float* v     = (const float*)d_in[2];
    const float* Wpre  = (const float*)d_in[3];
    const float* Wpost = (const float*)d_in[4];
    float* out = (float*)d_out;
    _Float16* shared = (_Float16*)((char*)d_ws + SH_OFF);   // Kh, then VT
    float*    lbuf   = (float*)((char*)d_ws + LB_OFF);
    _Float16* Ebuf   = (_Float16*)((char*)d_ws + E_OFF);

    if (ws_size >= WS_NEED) {
        prep_kh<<<dim3((B_ * H_ * N_ * D_) / (256 * 8)), dim3(256), 0, stream>>>(k, shared);
        hipMemsetAsync((char*)d_ws + LB_OFF, 0, LB_SZ, stream);
        attend_sweep1<<<dim3(512), dim3(512), 0, stream>>>(q, shared, Wpre, lbuf, Ebuf);
        prep_vt<<<dim3(B_ * H_ * (N_ / 64)), dim3(256), 0, stream>>>(v, shared);  // overwrites Kh
        attend_sweep2<<<dim3(1024), dim3(512), 0, stream>>>(Ebuf, shared, Wpost, lbuf, out);
    } else {
        attend_fused<<<dim3(B_ * 32), dim3(512), 0, stream>>>(q, k, v, Wpre, Wpost, out);
    }
}

// Round 15
// 163.983 us; speedup vs baseline: 1.0197x; 1.0197x over previous
//
#include <hip/hip_runtime.h>
#include <stdint.h>

#define B_  4
#define H_  16
#define N_  1024
#define D_  64
#define SS_R 328   // halfs per i-row of Ss: [i in 0..32)][j*20 + h], +8 pad
#define A2_R 328   // halfs per g-row of A2s: [g][i*20 + j], +8 pad

typedef _Float16 half4v __attribute__((ext_vector_type(4)));
typedef _Float16 half8v __attribute__((ext_vector_type(8)));
typedef float    f32x4  __attribute__((ext_vector_type(4)));

// workspace layout (bytes)
#define VT_OFF   0
#define VT_SZ    (B_ * H_ * D_ * N_ * 2)             // 8 MB
#define LB_OFF   (VT_OFF + VT_SZ)
#define LB_SZ    (B_ * H_ * N_ * 4)                  // 256 KB
#define E_OFF    (LB_OFF + LB_SZ)
#define E_SZ     ((size_t)B_ * 2080 * 4096 * 2)      // 65 MB causal-packed E
#define WS_NEED  ((size_t)E_OFF + E_SZ)              // 73.25 MB (proven available)

__device__ __forceinline__ half4v cvt4(f32x4 v) {
    half4v h;
    h[0] = (_Float16)v[0]; h[1] = (_Float16)v[1];
    h[2] = (_Float16)v[2]; h[3] = (_Float16)v[3];
    return h;
}

// decode blockIdx (0..511) -> slot grouped per XCD (consecutive slots same XCD)
__device__ __forceinline__ int xcd_slot(int x) { return (x >> 3) + (x & 7) * 64; }

// ---------------- prep: V transpose to f16 VT[b,h,d,j] ----------------
__global__ __launch_bounds__(256)
void prep_vt(const float* __restrict__ v, _Float16* __restrict__ VT) {
    __shared__ float T[64 * 67];
    const int t = threadIdx.x;
    const int bh = blockIdx.x >> 4, jb = blockIdx.x & 15, j0 = jb * 64;
    const float* src = v + ((size_t)bh * N_ + j0) * D_;
    #pragma unroll
    for (int m = 0; m < 4; ++m) {
        const int flat = m * 1024 + t * 4;
        const int j = flat >> 6, d0 = flat & 63;
        f32x4 val = *(const f32x4*)(src + flat);
        #pragma unroll
        for (int e = 0; e < 4; ++e) T[j * 67 + d0 + e] = val[e];
    }
    __syncthreads();
    const int d = t >> 2, jq = t & 3;
    half8v a, b2;
    #pragma unroll
    for (int jj = 0; jj < 8; ++jj) a[jj]  = (_Float16)T[(16 * jq + jj) * 67 + d];
    #pragma unroll
    for (int jj = 0; jj < 8; ++jj) b2[jj] = (_Float16)T[(16 * jq + 8 + jj) * 67 + d];
    _Float16* dst = VT + ((size_t)bh * D_ + d) * N_ + j0 + jq * 16;
    *(half8v*)dst = a;
    *(half8v*)(dst + 8) = b2;
}

// ---------------- sweep 1: l (atomic) + E cache (f16, causal-packed) ----------------
// grid 512: phased mirror-pairs. Cross-barrier K prefetch (next body's kf issued
// before the barrier, consumed after barrier + mix ~500cyc later).
// E tile layout (halfs, 4096/tile): (i&7)*512 + j*32 + (h>>2)*8 + (i>>3)*4 + (h&3)
__global__ __launch_bounds__(512, 2)
void attend_sweep1(const float* __restrict__ q, const float* __restrict__ k,
                   const float* __restrict__ Wpre, float* __restrict__ lbuf,
                   _Float16* __restrict__ Ebuf) {
    __shared__ _Float16 Ss[2][32 * SS_R];   // 41,984 B

    const int slot = xcd_slot(blockIdx.x);
    const int b = slot >> 7;
    const int r7 = slot & 127;
    const int m = r7 >> 2, phase = r7 & 3;
    const int itA = m, itB = 63 - m;
    const int i0A = m * 16, i0B = itB * 16;
    const int triA = itA * (itA + 1) / 2, triB = itB * (itB + 1) / 2;

    const int t = threadIdx.x;
    const int lane = t & 63, w = t >> 6;        // 8 waves
    const int l16 = lane & 15, lg = lane >> 4;
    const int h0 = 2 * w;
    const size_t bh0 = (size_t)b * H_;
    _Float16* Eb = Ebuf + (size_t)b * 2080 * 4096;

    const half4v wpre_f = cvt4(*(const f32x4*)(Wpre + l16 * 16 + 4 * lg));

    half4v qf[2][2][4];
    #pragma unroll
    for (int s = 0; s < 2; ++s) {
        const int i0s = s ? i0B : i0A;
        #pragma unroll
        for (int e = 0; e < 2; ++e) {
            const float* qrow = q + ((bh0 + h0 + e) * N_ + i0s + l16) * D_;
            #pragma unroll
            for (int kk = 0; kk < 4; ++kk) {
                f32x4 qv = *(const f32x4*)(qrow + kk * 16 + 4 * lg);
                half4v hv;
                #pragma unroll
                for (int xx = 0; xx < 4; ++xx) hv[xx] = (_Float16)(qv[xx] * 0.125f);
                qf[s][e][kk] = hv;
            }
        }
    }

    float lp[4][4];
    #pragma unroll
    for (int ss = 0; ss < 4; ++ss)
        #pragma unroll
        for (int r = 0; r < 4; ++r) lp[ss][r] = 0.f;

    // K row base pointers (per wave-head), advanced by jt*16*D
    const float* kbase0 = k + ((bh0 + h0 + 0) * N_ + l16) * D_ + 4 * lg;
    const float* kbase1 = k + ((bh0 + h0 + 1) * N_ + l16) * D_ + 4 * lg;

    // flattened jt sequence: jt(m_) = 2*(phase + 4*(m_>>1)) + (m_&1)
    #define JT_OF(m_) (2 * (phase + 4 * ((m_) >> 1)) + ((m_) & 1))

    int jt = JT_OF(0);
    if (jt <= itB) {
        int pbuf = 0;
        // prologue: K fragments for first body
        half4v kfc[2][4];
        #pragma unroll
        for (int kk = 0; kk < 4; ++kk) {
            kfc[0][kk] = cvt4(*(const f32x4*)(kbase0 + (size_t)jt * 16 * D_ + kk * 16));
            kfc[1][kk] = cvt4(*(const f32x4*)(kbase1 + (size_t)jt * 16 * D_ + kk * 16));
        }
        for (int m_ = 0; ; ++m_) {
            const bool actA = (jt <= itA);
            // QK^T -> Ss[pbuf] using current kf
            #pragma unroll
            for (int s = 0; s < 2; ++s) {
                if (s == 0 && !actA) continue;
                #pragma unroll
                for (int e = 0; e < 2; ++e) {
                    f32x4 acc = {0.f, 0.f, 0.f, 0.f};
                    #pragma unroll
                    for (int kk = 0; kk < 4; ++kk)
                        acc = __builtin_amdgcn_mfma_f32_16x16x16f16(qf[s][e][kk], kfc[e][kk], acc, 0, 0, 0);
                    #pragma unroll
                    for (int r = 0; r < 4; ++r)
                        Ss[pbuf][(s * 16 + 4 * lg + r) * SS_R + l16 * 20 + h0 + e] = (_Float16)acc[r];
                }
            }
            // prefetch next body's K (in flight across barrier + mix)
            const int jn = JT_OF(m_ + 1);
            const bool have_next = (jn <= itB);
            half4v kfn[2][4];
            if (have_next) {
                #pragma unroll
                for (int kk = 0; kk < 4; ++kk) {
                    kfn[0][kk] = cvt4(*(const f32x4*)(kbase0 + (size_t)jn * 16 * D_ + kk * 16));
                    kfn[1][kk] = cvt4(*(const f32x4*)(kbase1 + (size_t)jn * 16 * D_ + kk * 16));
                }
            }
            __syncthreads();
            // mix1 -> exp/mask -> E store + l accumulate
            #pragma unroll
            for (int ss = 0; ss < 4; ++ss) {
                const int strip = ss >> 1;
                if (strip == 0 && !actA) continue;
                const int sii = (ss & 1) * 8 + w;
                const int its = strip ? itB : itA;
                const int tri = strip ? triB : triA;
                half4v sfrag = *(const half4v*)&Ss[pbuf][(strip * 16 + sii) * SS_R + l16 * 20 + 4 * lg];
                f32x4 z = {0.f, 0.f, 0.f, 0.f};
                f32x4 m1 = __builtin_amdgcn_mfma_f32_16x16x16f16(wpre_f, sfrag, z, 0, 0, 0);
                const bool ok = (jt < its) || (l16 <= sii);
                half4v ev;
                #pragma unroll
                for (int r = 0; r < 4; ++r) {
                    const float e_ = ok ? __expf(m1[r]) : 0.f;
                    lp[ss][r] += e_;
                    ev[r] = (_Float16)e_;
                }
                *(half4v*)(Eb + (size_t)(tri + jt) * 4096 + w * 512 + l16 * 32 + lg * 8 + (ss & 1) * 4) = ev;
            }
            pbuf ^= 1;
            if (!have_next) break;
            jt = jn;
            #pragma unroll
            for (int kk = 0; kk < 4; ++kk) {
                kfc[0][kk] = kfn[0][kk];
                kfc[1][kk] = kfn[1][kk];
            }
        }
    }
    #undef JT_OF

    #pragma unroll
    for (int ss = 0; ss < 4; ++ss) {
        const int strip = ss >> 1;
        const int sii = (ss & 1) * 8 + w;
        const int i0s = strip ? i0B : i0A;
        #pragma unroll
        for (int r = 0; r < 4; ++r) {
            float val = lp[ss][r];
            val += __shfl_xor(val, 1, 64);
            val += __shfl_xor(val, 2, 64);
            val += __shfl_xor(val, 4, 64);
            val += __shfl_xor(val, 8, 64);
            if (l16 == 0)
                atomicAdd(&lbuf[(bh0 + 4 * lg + r) * N_ + i0s + sii], val);
        }
    }
}

// ---------------- sweep 2: out = Wpost·(E/l)·V — 2-deep E / 1-deep VT prefetch ----------------
// grid 1024: r=x>>4 balanced pairing, (b, d-quarter)=x&15. 16B E loads.
__global__ __launch_bounds__(512, 8)
void attend_sweep2(const _Float16* __restrict__ Ebuf, const _Float16* __restrict__ VT,
                   const float* __restrict__ Wpost, const float* __restrict__ lbuf,
                   float* __restrict__ out) {
    __shared__ _Float16 A2s[2][16 * A2_R];   // 20,992 B

    const int x = blockIdx.x;
    const int r_ = x >> 4;
    const int it = (r_ < 32) ? (63 - r_) : (r_ - 32);   // quadruple sums constant
    const int sub = x & 15;
    const int b = sub >> 2, dq = sub & 3;
    const int i0 = it * 16;

    const int t = threadIdx.x;
    const int lane = t & 63, w = t >> 6;      // 8 waves
    const int l16 = lane & 15, lg = lane >> 4;
    const int h0 = 2 * w;
    const size_t bh0 = (size_t)b * H_;

    const half4v wpost_f = cvt4(*(const f32x4*)(Wpost + l16 * 16 + 4 * lg));

    // 1/l for softmax head 4lg+r at rows i0+sii (sii = ss*8+w)
    float lrecip[2][4];
    #pragma unroll
    for (int ss = 0; ss < 2; ++ss) {
        const int sii = ss * 8 + w;
        #pragma unroll
        for (int r = 0; r < 4; ++r)
            lrecip[ss][r] = 1.0f / lbuf[(bh0 + 4 * lg + r) * N_ + i0 + sii];
    }

    const _Float16* Eb = Ebuf + ((size_t)b * 2080 + (size_t)it * (it + 1) / 2) * 4096
                       + w * 512 + l16 * 32 + lg * 8;
    const _Float16* vb0 = VT + ((bh0 + h0 + 0) * D_ + dq * 16 + l16) * (size_t)N_ + 4 * lg;
    const _Float16* vb1 = VT + ((bh0 + h0 + 1) * D_ + dq * 16 + l16) * (size_t)N_ + 4 * lg;

    f32x4 oacc[2];
    #pragma unroll
    for (int e = 0; e < 2; ++e) oacc[e] = (f32x4){0.f, 0.f, 0.f, 0.f};

    int pb = 0;
    // prologue: E(0), E(1) (2-deep), VT(0)
    half8v e0 = *(const half8v*)(Eb);
    half8v e1 = (it >= 1) ? *(const half8v*)(Eb + 4096) : e0;
    half4v vc[2];
    vc[0] = *(const half4v*)(vb0);
    vc[1] = *(const half4v*)(vb1);

    for (int jt = 0; jt <= it; ++jt) {
        // issue deep prefetches first: E(jt+2), VT(jt+1) — consumed 1-2 phases later
        half8v e2 = e1;
        if (jt + 2 <= it) e2 = *(const half8v*)(Eb + (size_t)(jt + 2) * 4096);
        half4v vn[2];
        if (jt + 1 <= it) {
            vn[0] = *(const half4v*)(vb0 + (jt + 1) * 16);
            vn[1] = *(const half4v*)(vb1 + (jt + 1) * 16);
        } else {
            vn[0] = vc[0]; vn[1] = vc[1];
        }
        // mix2 from 2-phase-old prefetched E
        #pragma unroll
        for (int ss = 0; ss < 2; ++ss) {
            const int sii = ss * 8 + w;
            half4v pf;
            #pragma unroll
            for (int r = 0; r < 4; ++r)
                pf[r] = (_Float16)((float)e0[ss * 4 + r] * lrecip[ss][r]);
            f32x4 z = {0.f, 0.f, 0.f, 0.f};
            f32x4 m2 = __builtin_amdgcn_mfma_f32_16x16x16f16(wpost_f, pf, z, 0, 0, 0);
            #pragma unroll
            for (int r = 0; r < 4; ++r)
                A2s[pb][(4 * lg + r) * A2_R + sii * 20 + l16] = (_Float16)m2[r];
        }
        __syncthreads();
        // PV with 1-phase-old prefetched VT
        #pragma unroll
        for (int e = 0; e < 2; ++e) {
            const int g = h0 + e;
            half4v bfrag = *(const half4v*)&A2s[pb][g * A2_R + l16 * 20 + 4 * lg];
            oacc[e] = __builtin_amdgcn_mfma_f32_16x16x16f16(vc[e], bfrag, oacc[e], 0, 0, 0);
        }
        e0 = e1; e1 = e2;
        vc[0] = vn[0]; vc[1] = vn[1];
        pb ^= 1;
    }

    // plain stores — WG exclusively owns (b, it-rows, all g, this d-quarter)
    #pragma unroll
    for (int e = 0; e < 2; ++e) {
        float* orow = out + ((bh0 + h0 + e) * N_ + i0 + l16) * D_;
        *(f32x4*)&orow[dq * 16 + 4 * lg] = oacc[e];
    }
}

// ---------------- fallback: fused mirror-pair kernel (ws-free, verified R6) ----------------
__global__ __launch_bounds__(512, 2)
void attend_fused(const float* __restrict__ q, const float* __restrict__ k,
                  const float* __restrict__ v, const float* __restrict__ Wpre,
                  const float* __restrict__ Wpost, float* __restrict__ out) {
    __shared__ _Float16 Ss[32 * SS_R];
    __shared__ _Float16 A2s[16 * 648];

    const int t = threadIdx.x;
    const int b = blockIdx.x >> 5;
    const int m = blockIdx.x & 31;
    const int itA = m, itB = 63 - m;
    const int i0A = m * 16, i0B = (63 - m) * 16;

    const int lane = t & 63, w = t >> 6;
    const int l16 = lane & 15, lg = lane >> 4;
    const int h0 = 2 * w;
    const size_t bh0 = (size_t)b * H_;

    const half4v wpre_f  = cvt4(*(const f32x4*)(Wpre  + l16 * 16 + 4 * lg));
    const half4v wpost_f = cvt4(*(const f32x4*)(Wpost + l16 * 16 + 4 * lg));

    half4v qf[2][2][4];
    #pragma unroll
    for (int s = 0; s < 2; ++s) {
        const int i0s = s ? i0B : i0A;
        #pragma unroll
        for (int e = 0; e < 2; ++e) {
            const float* qrow = q + ((bh0 + h0 + e) * N_ + i0s + l16) * D_;
            #pragma unroll
            for (int kk = 0; kk < 4; ++kk) {
                f32x4 qv = *(const f32x4*)(qrow + kk * 16 + 4 * lg);
                half4v hv;
                #pragma unroll
                for (int xx = 0; xx < 4; ++xx) hv[xx] = (_Float16)(qv[xx] * 0.125f);
                qf[s][e][kk] = hv;
            }
        }
    }

    float lp[4][4];
    #pragma unroll
    for (int ss = 0; ss < 4; ++ss)
        #pragma unroll
        for (int r = 0; r < 4; ++r) lp[ss][r] = 0.f;

    for (int jt = 0; jt <= itB; ++jt) {
        const int j0 = jt * 16;
        const bool actA = (jt <= itA);
        half4v kf[2][4];
        #pragma unroll
        for (int e = 0; e < 2; ++e) {
            const float* krow = k + ((bh0 + h0 + e) * N_ + j0 + l16) * D_ + 4 * lg;
            #pragma unroll
            for (int kk = 0; kk < 4; ++kk) kf[e][kk] = cvt4(*(const f32x4*)(krow + kk * 16));
        }
        #pragma unroll
        for (int s = 0; s < 2; ++s) {
            if (s == 0 && !actA) continue;
            #pragma unroll
            for (int e = 0; e < 2; ++e) {
                f32x4 acc = {0.f, 0.f, 0.f, 0.f};
                #pragma unroll
                for (int kk = 0; kk < 4; ++kk)
                    acc = __builtin_amdgcn_mfma_f32_16x16x16f16(qf[s][e][kk], kf[e][kk], acc, 0, 0, 0);
                #pragma unroll
                for (int r = 0; r < 4; ++r)
                    Ss[(s * 16 + 4 * lg + r) * SS_R + l16 * 20 + h0 + e] = (_Float16)acc[r];
            }
        }
        __syncthreads();
        #pragma unroll
        for (int ss = 0; ss < 4; ++ss) {
            const int strip = ss >> 1;
            if (strip == 0 && !actA) continue;
            const int sii = (ss & 1) * 8 + w;
            const int its = strip ? itB : itA;
            half4v sfrag = *(const half4v*)&Ss[(strip * 16 + sii) * SS_R + l16 * 20 + 4 * lg];
            f32x4 z = {0.f, 0.f, 0.f, 0.f};
            f32x4 m1 = __builtin_amdgcn_mfma_f32_16x16x16f16(wpre_f, sfrag, z, 0, 0, 0);
            if ((jt < its) || (l16 <= sii)) {
                #pragma unroll
                for (int r = 0; r < 4; ++r) lp[ss][r] += __expf(m1[r]);
            }
        }
        __syncthreads();
    }

    float lrec[4][4];
    #pragma unroll
    for (int ss = 0; ss < 4; ++ss)
        #pragma unroll
        for (int r = 0; r < 4; ++r) {
            float val = lp[ss][r];
            val += __shfl_xor(val, 1, 64);
            val += __shfl_xor(val, 2, 64);
            val += __shfl_xor(val, 4, 64);
            val += __shfl_xor(val, 8, 64);
            lrec[ss][r] = 1.0f / val;
        }

    f32x4 oacc[2][2][4];
    #pragma unroll
    for (int s = 0; s < 2; ++s)
        #pragma unroll
        for (int e = 0; e < 2; ++e)
            #pragma unroll
            for (int ds = 0; ds < 4; ++ds)
                oacc[s][e][ds] = (f32x4){0.f, 0.f, 0.f, 0.f};

    for (int jt = 0; jt <= itB; ++jt) {
        const int j0 = jt * 16;
        const bool actA = (jt <= itA);
        half4v kf[2][4];
        #pragma unroll
        for (int e = 0; e < 2; ++e) {
            const float* krow = k + ((bh0 + h0 + e) * N_ + j0 + l16) * D_ + 4 * lg;
            #pragma unroll
            for (int kk = 0; kk < 4; ++kk) kf[e][kk] = cvt4(*(const f32x4*)(krow + kk * 16));
        }
        half4v vf[2][4];
        #pragma unroll
        for (int e = 0; e < 2; ++e)
            #pragma unroll
            for (int ds = 0; ds < 4; ++ds) {
                f32x4 vv;
                #pragma unroll
                for (int xx = 0; xx < 4; ++xx)
                    vv[xx] = v[((bh0 + h0 + e) * N_ + j0 + 4 * lg + xx) * D_ + ds * 16 + l16];
                vf[e][ds] = cvt4(vv);
            }
        #pragma unroll
        for (int s = 0; s < 2; ++s) {
            if (s == 0 && !actA) continue;
            #pragma unroll
            for (int e = 0; e < 2; ++e) {
                f32x4 acc = {0.f, 0.f, 0.f, 0.f};
                #pragma unroll
                for (int kk = 0; kk < 4; ++kk)
                    acc = __builtin_amdgcn_mfma_f32_16x16x16f16(qf[s][e][kk], kf[e][kk], acc, 0, 0, 0);
                #pragma unroll
                for (int r = 0; r < 4; ++r)
                    Ss[(s * 16 + 4 * lg + r) * SS_R + l16 * 20 + h0 + e] = (_Float16)acc[r];
            }
        }
        __syncthreads();
        #pragma unroll
        for (int ss = 0; ss < 4; ++ss) {
            const int strip = ss >> 1;
            if (strip == 0 && !actA) continue;
            const int sii = (ss & 1) * 8 + w;
            const int its = strip ? itB : itA;
            half4v sfrag = *(const half4v*)&Ss[(strip * 16 + sii) * SS_R + l16 * 20 + 4 * lg];
            f32x4 z = {0.f, 0.f, 0.f, 0.f};
            f32x4 m1 = __builtin_amdgcn_mfma_f32_16x16x16f16(wpre_f, sfrag, z, 0, 0, 0);
            const bool ok = (jt < its) || (l16 <= sii);
            half4v pfrag;
            #pragma unroll
            for (int r = 0; r < 4; ++r)
                pfrag[r] = (_Float16)(ok ? __expf(m1[r]) * lrec[ss][r] : 0.f);
            f32x4 m2 = __builtin_amdgcn_mfma_f32_16x16x16f16(wpost_f, pfrag, z, 0, 0, 0);
            #pragma unroll
            for (int r = 0; r < 4; ++r)
                A2s[(4 * lg + r) * 648 + (strip * 16 + sii) * 20 + l16] = (_Float16)m2[r];
        }
        __syncthreads();
        #pragma unroll
        for (int s = 0; s < 2; ++s) {
            if (s == 0 && !actA) continue;
            #pragma unroll
            for (int e = 0; e < 2; ++e) {
                half4v bfrag = *(const half4v*)&A2s[(h0 + e) * 648 + (s * 16 + l16) * 20 + 4 * lg];
                #pragma unroll
                for (int ds = 0; ds < 4; ++ds)
                    oacc[s][e][ds] = __builtin_amdgcn_mfma_f32_16x16x16f16(vf[e][ds], bfrag, oacc[s][e][ds], 0, 0, 0);
            }
        }
    }

    #pragma unroll
    for (int s = 0; s < 2; ++s) {
        const int i0s = s ? i0B : i0A;
        #pragma unroll
        for (int e = 0; e < 2; ++e) {
            float* orow = out + ((bh0 + h0 + e) * N_ + i0s + l16) * D_;
            #pragma unroll
            for (int ds = 0; ds < 4; ++ds)
                *(f32x4*)&orow[ds * 16 + 4 * lg] = oacc[s][e][ds];
        }
    }
}

extern "C" void kernel_launch(void* const* d_in, const int* in_sizes, int n_in,
                              void* d_out, int out_size, void* d_ws, size_t ws_size,
                              hipStream_t stream) {
    const float* q     = (const float*)d_in[0];
    const float* k     = (const float*)d_in[1];
    const float* v     = (const float*)d_in[2];
    const float* Wpre  = (const float*)d_in[3];
    const float* Wpost = (const float*)d_in[4];
    float* out = (float*)d_out;
    _Float16* VT   = (_Float16*)((char*)d_ws + VT_OFF);
    float*    lbuf = (float*)((char*)d_ws + LB_OFF);
    _Float16* Ebuf = (_Float16*)((char*)d_ws + E_OFF);

    if (ws_size >= WS_NEED) {
        prep_vt<<<dim3(B_ * H_ * (N_ / 64)), dim3(256), 0, stream>>>(v, VT);
        hipMemsetAsync((char*)d_ws + LB_OFF, 0, LB_SZ, stream);
        attend_sweep1<<<dim3(512), dim3(512), 0, stream>>>(q, k, Wpre, lbuf, Ebuf);
        attend_sweep2<<<dim3(1024), dim3(512), 0, stream>>>(Ebuf, VT, Wpost, lbuf, out);
    } else {
        attend_fused<<<dim3(B_ * 32), dim3(512), 0, stream>>>(q, k, v, Wpre, Wpost, out);
    }
}

// Round 16
// 146.767 us; speedup vs baseline: 1.1394x; 1.1173x over previous
//
#include <hip/hip_runtime.h>
#include <stdint.h>

#define B_  4
#define H_  16
#define N_  1024
#define D_  64
#define SS_R 328   // halfs per i-row of Ss: [i in 0..32)][j*20 + h], +8 pad
#define A2_R 328   // halfs per g-row of A2s: [g][i*20 + j], +8 pad

typedef _Float16 half4v __attribute__((ext_vector_type(4)));
typedef _Float16 half8v __attribute__((ext_vector_type(8)));
typedef float    f32x4  __attribute__((ext_vector_type(4)));

// workspace layout (bytes)
#define VT_OFF   0
#define VT_SZ    (B_ * H_ * D_ * N_ * 2)             // 8 MB
#define LB_OFF   (VT_OFF + VT_SZ)
#define LB_SZ    (B_ * H_ * N_ * 4)                  // 256 KB
#define E_OFF    (LB_OFF + LB_SZ)
#define E_SZ     ((size_t)B_ * 2080 * 4096 * 2)      // 65 MB causal-packed E
#define WS_NEED  ((size_t)E_OFF + E_SZ)              // 73.25 MB (proven available)

__device__ __forceinline__ half4v cvt4(f32x4 v) {
    half4v h;
    h[0] = (_Float16)v[0]; h[1] = (_Float16)v[1];
    h[2] = (_Float16)v[2]; h[3] = (_Float16)v[3];
    return h;
}

// decode blockIdx (0..511) -> slot grouped per XCD (consecutive slots same XCD)
__device__ __forceinline__ int xcd_slot(int x) { return (x >> 3) + (x & 7) * 64; }

// ---------------- prep: V transpose to f16 VT[b,h,d,j] ----------------
__global__ __launch_bounds__(256)
void prep_vt(const float* __restrict__ v, _Float16* __restrict__ VT) {
    __shared__ float T[64 * 67];
    const int t = threadIdx.x;
    const int bh = blockIdx.x >> 4, jb = blockIdx.x & 15, j0 = jb * 64;
    const float* src = v + ((size_t)bh * N_ + j0) * D_;
    #pragma unroll
    for (int m = 0; m < 4; ++m) {
        const int flat = m * 1024 + t * 4;
        const int j = flat >> 6, d0 = flat & 63;
        f32x4 val = *(const f32x4*)(src + flat);
        #pragma unroll
        for (int e = 0; e < 4; ++e) T[j * 67 + d0 + e] = val[e];
    }
    __syncthreads();
    const int d = t >> 2, jq = t & 3;
    half8v a, b2;
    #pragma unroll
    for (int jj = 0; jj < 8; ++jj) a[jj]  = (_Float16)T[(16 * jq + jj) * 67 + d];
    #pragma unroll
    for (int jj = 0; jj < 8; ++jj) b2[jj] = (_Float16)T[(16 * jq + 8 + jj) * 67 + d];
    _Float16* dst = VT + ((size_t)bh * D_ + d) * N_ + j0 + jq * 16;
    *(half8v*)dst = a;
    *(half8v*)(dst + 8) = b2;
}

// ---------------- sweep 1: l (atomic) + E cache (f16, causal-packed) ----------------
// grid 512: phased mirror-pairs, cross-barrier K prefetch (R15-proven).
// E tile layout (halfs, 4096/tile): (i&7)*512 + j*32 + (h>>2)*8 + (i>>3)*4 + (h&3)
__global__ __launch_bounds__(512, 2)
void attend_sweep1(const float* __restrict__ q, const float* __restrict__ k,
                   const float* __restrict__ Wpre, float* __restrict__ lbuf,
                   _Float16* __restrict__ Ebuf) {
    __shared__ _Float16 Ss[2][32 * SS_R];   // 41,984 B

    const int slot = xcd_slot(blockIdx.x);
    const int b = slot >> 7;
    const int r7 = slot & 127;
    const int m = r7 >> 2, phase = r7 & 3;
    const int itA = m, itB = 63 - m;
    const int i0A = m * 16, i0B = itB * 16;
    const int triA = itA * (itA + 1) / 2, triB = itB * (itB + 1) / 2;

    const int t = threadIdx.x;
    const int lane = t & 63, w = t >> 6;        // 8 waves
    const int l16 = lane & 15, lg = lane >> 4;
    const int h0 = 2 * w;
    const size_t bh0 = (size_t)b * H_;
    _Float16* Eb = Ebuf + (size_t)b * 2080 * 4096;

    const half4v wpre_f = cvt4(*(const f32x4*)(Wpre + l16 * 16 + 4 * lg));

    half4v qf[2][2][4];
    #pragma unroll
    for (int s = 0; s < 2; ++s) {
        const int i0s = s ? i0B : i0A;
        #pragma unroll
        for (int e = 0; e < 2; ++e) {
            const float* qrow = q + ((bh0 + h0 + e) * N_ + i0s + l16) * D_;
            #pragma unroll
            for (int kk = 0; kk < 4; ++kk) {
                f32x4 qv = *(const f32x4*)(qrow + kk * 16 + 4 * lg);
                half4v hv;
                #pragma unroll
                for (int xx = 0; xx < 4; ++xx) hv[xx] = (_Float16)(qv[xx] * 0.125f);
                qf[s][e][kk] = hv;
            }
        }
    }

    float lp[4][4];
    #pragma unroll
    for (int ss = 0; ss < 4; ++ss)
        #pragma unroll
        for (int r = 0; r < 4; ++r) lp[ss][r] = 0.f;

    const float* kbase0 = k + ((bh0 + h0 + 0) * N_ + l16) * D_ + 4 * lg;
    const float* kbase1 = k + ((bh0 + h0 + 1) * N_ + l16) * D_ + 4 * lg;

    #define JT_OF(m_) (2 * (phase + 4 * ((m_) >> 1)) + ((m_) & 1))

    int jt = JT_OF(0);
    if (jt <= itB) {
        int pbuf = 0;
        half4v kfc[2][4];
        #pragma unroll
        for (int kk = 0; kk < 4; ++kk) {
            kfc[0][kk] = cvt4(*(const f32x4*)(kbase0 + (size_t)jt * 16 * D_ + kk * 16));
            kfc[1][kk] = cvt4(*(const f32x4*)(kbase1 + (size_t)jt * 16 * D_ + kk * 16));
        }
        for (int m_ = 0; ; ++m_) {
            const bool actA = (jt <= itA);
            #pragma unroll
            for (int s = 0; s < 2; ++s) {
                if (s == 0 && !actA) continue;
                #pragma unroll
                for (int e = 0; e < 2; ++e) {
                    f32x4 acc = {0.f, 0.f, 0.f, 0.f};
                    #pragma unroll
                    for (int kk = 0; kk < 4; ++kk)
                        acc = __builtin_amdgcn_mfma_f32_16x16x16f16(qf[s][e][kk], kfc[e][kk], acc, 0, 0, 0);
                    #pragma unroll
                    for (int r = 0; r < 4; ++r)
                        Ss[pbuf][(s * 16 + 4 * lg + r) * SS_R + l16 * 20 + h0 + e] = (_Float16)acc[r];
                }
            }
            const int jn = JT_OF(m_ + 1);
            const bool have_next = (jn <= itB);
            half4v kfn[2][4];
            if (have_next) {
                #pragma unroll
                for (int kk = 0; kk < 4; ++kk) {
                    kfn[0][kk] = cvt4(*(const f32x4*)(kbase0 + (size_t)jn * 16 * D_ + kk * 16));
                    kfn[1][kk] = cvt4(*(const f32x4*)(kbase1 + (size_t)jn * 16 * D_ + kk * 16));
                }
            }
            __syncthreads();
            #pragma unroll
            for (int ss = 0; ss < 4; ++ss) {
                const int strip = ss >> 1;
                if (strip == 0 && !actA) continue;
                const int sii = (ss & 1) * 8 + w;
                const int its = strip ? itB : itA;
                const int tri = strip ? triB : triA;
                half4v sfrag = *(const half4v*)&Ss[pbuf][(strip * 16 + sii) * SS_R + l16 * 20 + 4 * lg];
                f32x4 z = {0.f, 0.f, 0.f, 0.f};
                f32x4 m1 = __builtin_amdgcn_mfma_f32_16x16x16f16(wpre_f, sfrag, z, 0, 0, 0);
                const bool ok = (jt < its) || (l16 <= sii);
                half4v ev;
                #pragma unroll
                for (int r = 0; r < 4; ++r) {
                    const float e_ = ok ? __expf(m1[r]) : 0.f;
                    lp[ss][r] += e_;
                    ev[r] = (_Float16)e_;
                }
                *(half4v*)(Eb + (size_t)(tri + jt) * 4096 + w * 512 + l16 * 32 + lg * 8 + (ss & 1) * 4) = ev;
            }
            pbuf ^= 1;
            if (!have_next) break;
            jt = jn;
            #pragma unroll
            for (int kk = 0; kk < 4; ++kk) {
                kfc[0][kk] = kfn[0][kk];
                kfc[1][kk] = kfn[1][kk];
            }
        }
    }
    #undef JT_OF

    #pragma unroll
    for (int ss = 0; ss < 4; ++ss) {
        const int strip = ss >> 1;
        const int sii = (ss & 1) * 8 + w;
        const int i0s = strip ? i0B : i0A;
        #pragma unroll
        for (int r = 0; r < 4; ++r) {
            float val = lp[ss][r];
            val += __shfl_xor(val, 1, 64);
            val += __shfl_xor(val, 2, 64);
            val += __shfl_xor(val, 4, 64);
            val += __shfl_xor(val, 8, 64);
            if (l16 == 0)
                atomicAdd(&lbuf[(bh0 + 4 * lg + r) * N_ + i0s + sii], val);
        }
    }
}

// ---------------- sweep 2: mirror-pair strips share VT reads ----------------
// grid 512: WG = (b, pair m, dq). Long strip B (it=63-m) + short strip A (it=m):
// one VT fragment load feeds both strips' PV -> VT L3 traffic cut ~2.7x.
// Balance: block x pairs with x+256 carrying complementary m (chain sums const).
__global__ __launch_bounds__(512, 4)
void attend_sweep2(const _Float16* __restrict__ Ebuf, const _Float16* __restrict__ VT,
                   const float* __restrict__ Wpost, const float* __restrict__ lbuf,
                   float* __restrict__ out) {
    __shared__ _Float16 A2sA[2][16 * A2_R];   // 20,992 B
    __shared__ _Float16 A2sB[2][16 * A2_R];   // 20,992 B

    const int x = blockIdx.x;
    const int xm = x >> 4;
    const int m = (x < 256) ? xm : (31 - (xm & 15));   // x and x+256: complementary m
    const int sub = x & 15;
    const int b = sub >> 2, dq = sub & 3;
    const int itA = m, itB = 63 - m;
    const int i0A = m * 16, i0B = itB * 16;

    const int t = threadIdx.x;
    const int lane = t & 63, w = t >> 6;      // 8 waves
    const int l16 = lane & 15, lg = lane >> 4;
    const int h0 = 2 * w;
    const size_t bh0 = (size_t)b * H_;

    const half4v wpost_f = cvt4(*(const f32x4*)(Wpost + l16 * 16 + 4 * lg));

    // 1/l per strip: softmax head 4lg+r at rows i0+sii (sii = ss*8+w)
    float lrA[2][4], lrB[2][4];
    #pragma unroll
    for (int ss = 0; ss < 2; ++ss) {
        const int sii = ss * 8 + w;
        #pragma unroll
        for (int r = 0; r < 4; ++r) {
            lrA[ss][r] = 1.0f / lbuf[(bh0 + 4 * lg + r) * N_ + i0A + sii];
            lrB[ss][r] = 1.0f / lbuf[(bh0 + 4 * lg + r) * N_ + i0B + sii];
        }
    }

    const size_t lane_off = (size_t)w * 512 + l16 * 32 + lg * 8;
    const _Float16* EbA = Ebuf + ((size_t)b * 2080 + (size_t)itA * (itA + 1) / 2) * 4096 + lane_off;
    const _Float16* EbB = Ebuf + ((size_t)b * 2080 + (size_t)itB * (itB + 1) / 2) * 4096 + lane_off;
    const _Float16* vb0 = VT + ((bh0 + h0 + 0) * D_ + dq * 16 + l16) * (size_t)N_ + 4 * lg;
    const _Float16* vb1 = VT + ((bh0 + h0 + 1) * D_ + dq * 16 + l16) * (size_t)N_ + 4 * lg;

    f32x4 oaccA[2], oaccB[2];
    #pragma unroll
    for (int e = 0; e < 2; ++e) {
        oaccA[e] = (f32x4){0.f, 0.f, 0.f, 0.f};
        oaccB[e] = (f32x4){0.f, 0.f, 0.f, 0.f};
    }

    int pb = 0;
    // prologue: E(0) for both strips
    half8v eB = *(const half8v*)(EbB);
    half8v eA = *(const half8v*)(EbA);

    for (int jt = 0; jt <= itB; ++jt) {
        const bool actA = (jt <= itA);
        // VT fragments for this jt — shared by both strips (in flight under mix2+barrier)
        half4v vf[2];
        vf[0] = *(const half4v*)(vb0 + jt * 16);
        vf[1] = *(const half4v*)(vb1 + jt * 16);
        // prefetch next E (both strips) — consumed next body
        half8v eBn = eB, eAn = eA;
        if (jt < itB) eBn = *(const half8v*)(EbB + (size_t)(jt + 1) * 4096);
        if (jt < itA) eAn = *(const half8v*)(EbA + (size_t)(jt + 1) * 4096);
        // mix2 strip B
        #pragma unroll
        for (int ss = 0; ss < 2; ++ss) {
            const int sii = ss * 8 + w;
            half4v pf;
            #pragma unroll
            for (int r = 0; r < 4; ++r)
                pf[r] = (_Float16)((float)eB[ss * 4 + r] * lrB[ss][r]);
            f32x4 z = {0.f, 0.f, 0.f, 0.f};
            f32x4 m2 = __builtin_amdgcn_mfma_f32_16x16x16f16(wpost_f, pf, z, 0, 0, 0);
            #pragma unroll
            for (int r = 0; r < 4; ++r)
                A2sB[pb][(4 * lg + r) * A2_R + sii * 20 + l16] = (_Float16)m2[r];
        }
        // mix2 strip A (when active)
        if (actA) {
            #pragma unroll
            for (int ss = 0; ss < 2; ++ss) {
                const int sii = ss * 8 + w;
                half4v pf;
                #pragma unroll
                for (int r = 0; r < 4; ++r)
                    pf[r] = (_Float16)((float)eA[ss * 4 + r] * lrA[ss][r]);
                f32x4 z = {0.f, 0.f, 0.f, 0.f};
                f32x4 m2 = __builtin_amdgcn_mfma_f32_16x16x16f16(wpost_f, pf, z, 0, 0, 0);
                #pragma unroll
                for (int r = 0; r < 4; ++r)
                    A2sA[pb][(4 * lg + r) * A2_R + sii * 20 + l16] = (_Float16)m2[r];
            }
        }
        __syncthreads();
        // PV — one vf serves both strips
        #pragma unroll
        for (int e = 0; e < 2; ++e) {
            const int g = h0 + e;
            half4v bfB = *(const half4v*)&A2sB[pb][g * A2_R + l16 * 20 + 4 * lg];
            oaccB[e] = __builtin_amdgcn_mfma_f32_16x16x16f16(vf[e], bfB, oaccB[e], 0, 0, 0);
        }
        if (actA) {
            #pragma unroll
            for (int e = 0; e < 2; ++e) {
                const int g = h0 + e;
                half4v bfA = *(const half4v*)&A2sA[pb][g * A2_R + l16 * 20 + 4 * lg];
                oaccA[e] = __builtin_amdgcn_mfma_f32_16x16x16f16(vf[e], bfA, oaccA[e], 0, 0, 0);
            }
        }
        eB = eBn; eA = eAn;
        pb ^= 1;
    }

    // plain stores — both strips, this d-quarter
    #pragma unroll
    for (int e = 0; e < 2; ++e) {
        float* orowB = out + ((bh0 + h0 + e) * N_ + i0B + l16) * D_;
        *(f32x4*)&orowB[dq * 16 + 4 * lg] = oaccB[e];
        float* orowA = out + ((bh0 + h0 + e) * N_ + i0A + l16) * D_;
        *(f32x4*)&orowA[dq * 16 + 4 * lg] = oaccA[e];
    }
}

// ---------------- fallback: fused mirror-pair kernel (ws-free, verified R6) ----------------
__global__ __launch_bounds__(512, 2)
void attend_fused(const float* __restrict__ q, const float* __restrict__ k,
                  const float* __restrict__ v, const float* __restrict__ Wpre,
                  const float* __restrict__ Wpost, float* __restrict__ out) {
    __shared__ _Float16 Ss[32 * SS_R];
    __shared__ _Float16 A2s[16 * 648];

    const int t = threadIdx.x;
    const int b = blockIdx.x >> 5;
    const int m = blockIdx.x & 31;
    const int itA = m, itB = 63 - m;
    const int i0A = m * 16, i0B = (63 - m) * 16;

    const int lane = t & 63, w = t >> 6;
    const int l16 = lane & 15, lg = lane >> 4;
    const int h0 = 2 * w;
    const size_t bh0 = (size_t)b * H_;

    const half4v wpre_f  = cvt4(*(const f32x4*)(Wpre  + l16 * 16 + 4 * lg));
    const half4v wpost_f = cvt4(*(const f32x4*)(Wpost + l16 * 16 + 4 * lg));

    half4v qf[2][2][4];
    #pragma unroll
    for (int s = 0; s < 2; ++s) {
        const int i0s = s ? i0B : i0A;
        #pragma unroll
        for (int e = 0; e < 2; ++e) {
            const float* qrow = q + ((bh0 + h0 + e) * N_ + i0s + l16) * D_;
            #pragma unroll
            for (int kk = 0; kk < 4; ++kk) {
                f32x4 qv = *(const f32x4*)(qrow + kk * 16 + 4 * lg);
                half4v hv;
                #pragma unroll
                for (int xx = 0; xx < 4; ++xx) hv[xx] = (_Float16)(qv[xx] * 0.125f);
                qf[s][e][kk] = hv;
            }
        }
    }

    float lp[4][4];
    #pragma unroll
    for (int ss = 0; ss < 4; ++ss)
        #pragma unroll
        for (int r = 0; r < 4; ++r) lp[ss][r] = 0.f;

    for (int jt = 0; jt <= itB; ++jt) {
        const int j0 = jt * 16;
        const bool actA = (jt <= itA);
        half4v kf[2][4];
        #pragma unroll
        for (int e = 0; e < 2; ++e) {
            const float* krow = k + ((bh0 + h0 + e) * N_ + j0 + l16) * D_ + 4 * lg;
            #pragma unroll
            for (int kk = 0; kk < 4; ++kk) kf[e][kk] = cvt4(*(const f32x4*)(krow + kk * 16));
        }
        #pragma unroll
        for (int s = 0; s < 2; ++s) {
            if (s == 0 && !actA) continue;
            #pragma unroll
            for (int e = 0; e < 2; ++e) {
                f32x4 acc = {0.f, 0.f, 0.f, 0.f};
                #pragma unroll
                for (int kk = 0; kk < 4; ++kk)
                    acc = __builtin_amdgcn_mfma_f32_16x16x16f16(qf[s][e][kk], kf[e][kk], acc, 0, 0, 0);
                #pragma unroll
                for (int r = 0; r < 4; ++r)
                    Ss[(s * 16 + 4 * lg + r) * SS_R + l16 * 20 + h0 + e] = (_Float16)acc[r];
            }
        }
        __syncthreads();
        #pragma unroll
        for (int ss = 0; ss < 4; ++ss) {
            const int strip = ss >> 1;
            if (strip == 0 && !actA) continue;
            const int sii = (ss & 1) * 8 + w;
            const int its = strip ? itB : itA;
            half4v sfrag = *(const half4v*)&Ss[(strip * 16 + sii) * SS_R + l16 * 20 + 4 * lg];
            f32x4 z = {0.f, 0.f, 0.f, 0.f};
            f32x4 m1 = __builtin_amdgcn_mfma_f32_16x16x16f16(wpre_f, sfrag, z, 0, 0, 0);
            if ((jt < its) || (l16 <= sii)) {
                #pragma unroll
                for (int r = 0; r < 4; ++r) lp[ss][r] += __expf(m1[r]);
            }
        }
        __syncthreads();
    }

    float lrec[4][4];
    #pragma unroll
    for (int ss = 0; ss < 4; ++ss)
        #pragma unroll
        for (int r = 0; r < 4; ++r) {
            float val = lp[ss][r];
            val += __shfl_xor(val, 1, 64);
            val += __shfl_xor(val, 2, 64);
            val += __shfl_xor(val, 4, 64);
            val += __shfl_xor(val, 8, 64);
            lrec[ss][r] = 1.0f / val;
        }

    f32x4 oacc[2][2][4];
    #pragma unroll
    for (int s = 0; s < 2; ++s)
        #pragma unroll
        for (int e = 0; e < 2; ++e)
            #pragma unroll
            for (int ds = 0; ds < 4; ++ds)
                oacc[s][e][ds] = (f32x4){0.f, 0.f, 0.f, 0.f};

    for (int jt = 0; jt <= itB; ++jt) {
        const int j0 = jt * 16;
        const bool actA = (jt <= itA);
        half4v kf[2][4];
        #pragma unroll
        for (int e = 0; e < 2; ++e) {
            const float* krow = k + ((bh0 + h0 + e) * N_ + j0 + l16) * D_ + 4 * lg;
            #pragma unroll
            for (int kk = 0; kk < 4; ++kk) kf[e][kk] = cvt4(*(const f32x4*)(krow + kk * 16));
        }
        half4v vf[2][4];
        #pragma unroll
        for (int e = 0; e < 2; ++e)
            #pragma unroll
            for (int ds = 0; ds < 4; ++ds) {
                f32x4 vv;
                #pragma unroll
                for (int xx = 0; xx < 4; ++xx)
                    vv[xx] = v[((bh0 + h0 + e) * N_ + j0 + 4 * lg + xx) * D_ + ds * 16 + l16];
                vf[e][ds] = cvt4(vv);
            }
        #pragma unroll
        for (int s = 0; s < 2; ++s) {
            if (s == 0 && !actA) continue;
            #pragma unroll
            for (int e = 0; e < 2; ++e) {
                f32x4 acc = {0.f, 0.f, 0.f, 0.f};
                #pragma unroll
                for (int kk = 0; kk < 4; ++kk)
                    acc = __builtin_amdgcn_mfma_f32_16x16x16f16(qf[s][e][kk], kf[e][kk], acc, 0, 0, 0);
                #pragma unroll
                for (int r = 0; r < 4; ++r)
                    Ss[(s * 16 + 4 * lg + r) * SS_R + l16 * 20 + h0 + e] = (_Float16)acc[r];
            }
        }
        __syncthreads();
        #pragma unroll
        for (int ss = 0; ss < 4; ++ss) {
            const int strip = ss >> 1;
            if (strip == 0 && !actA) continue;
            const int sii = (ss & 1) * 8 + w;
            const int its = strip ? itB : itA;
            half4v sfrag = *(const half4v*)&Ss[(strip * 16 + sii) * SS_R + l16 * 20 + 4 * lg];
            f32x4 z = {0.f, 0.f, 0.f, 0.f};
            f32x4 m1 = __builtin_amdgcn_mfma_f32_16x16x16f16(wpre_f, sfrag, z, 0, 0, 0);
            const bool ok = (jt < its) || (l16 <= sii);
            half4v pfrag;
            #pragma unroll
            for (int r = 0; r < 4; ++r)
                pfrag[r] = (_Float16)(ok ? __expf(m1[r]) * lrec[ss][r] : 0.f);
            f32x4 m2 = __builtin_amdgcn_mfma_f32_16x16x16f16(wpost_f, pfrag, z, 0, 0, 0);
            #pragma unroll
            for (int r = 0; r < 4; ++r)
                A2s[(4 * lg + r) * 648 + (strip * 16 + sii) * 20 + l16] = (_Float16)m2[r];
        }
        __syncthreads();
        #pragma unroll
        for (int s = 0; s < 2; ++s) {
            if (s == 0 && !actA) continue;
            #pragma unroll
            for (int e = 0; e < 2; ++e) {
                half4v bfrag = *(const half4v*)&A2s[(h0 + e) * 648 + (s * 16 + l16) * 20 + 4 * lg];
                #pragma unroll
                for (int ds = 0; ds < 4; ++ds)
                    oacc[s][e][ds] = __builtin_amdgcn_mfma_f32_16x16x16f16(vf[e][ds], bfrag, oacc[s][e][ds], 0, 0, 0);
            }
        }
    }

    #pragma unroll
    for (int s = 0; s < 2; ++s) {
        const int i0s = s ? i0B : i0A;
        #pragma unroll
        for (int e = 0; e < 2; ++e) {
            float* orow = out + ((bh0 + h0 + e) * N_ + i0s + l16) * D_;
            #pragma unroll
            for (int ds = 0; ds < 4; ++ds)
                *(f32x4*)&orow[ds * 16 + 4 * lg] = oacc[s][e][ds];
        }
    }
}

extern "C" void kernel_launch(void* const* d_in, const int* in_sizes, int n_in,
                              void* d_out, int out_size, void* d_ws, size_t ws_size,
                              hipStream_t stream) {
    const float* q     = (const float*)d_in[0];
    const float* k     = (const float*)d_in[1];
    const float* v     = (const float*)d_in[2];
    const float* Wpre  = (const float*)d_in[3];
    const float* Wpost = (const float*)d_in[4];
    float* out = (float*)d_out;
    _Float16* VT   = (_Float16*)((char*)d_ws + VT_OFF);
    float*    lbuf = (float*)((char*)d_ws + LB_OFF);
    _Float16* Ebuf = (_Float16*)((char*)d_ws + E_OFF);

    if (ws_size >= WS_NEED) {
        prep_vt<<<dim3(B_ * H_ * (N_ / 64)), dim3(256), 0, stream>>>(v, VT);
        hipMemsetAsync((char*)d_ws + LB_OFF, 0, LB_SZ, stream);
        attend_sweep1<<<dim3(512), dim3(512), 0, stream>>>(q, k, Wpre, lbuf, Ebuf);
        attend_sweep2<<<dim3(512), dim3(512), 0, stream>>>(Ebuf, VT, Wpost, lbuf, out);
    } else {
        attend_fused<<<dim3(B_ * 32), dim3(512), 0, stream>>>(q, k, v, Wpre, Wpost, out);
    }
}